// Round 7
// baseline (84.261 us; speedup 1.0000x reference)
//
#include <hip/hip_runtime.h>
#include <hip/hip_bf16.h>
#include <stdint.h>

typedef __attribute__((ext_vector_type(8))) short bf16x8;
typedef __attribute__((ext_vector_type(4))) float f32x4;
using bf16 = __hip_bfloat16;

static constexpr int Mdim = 512;   // A batch
static constexpr int Ndim = 64;    // B batch
static constexpr int Cdim = 128;   // channels (K of the GEMM)
static constexpr int Pdim = 64;    // H*W positions
static constexpr float EPS_ADD = 0.001f;

// ---------------------------------------------------------------------------
// async global->LDS, 16B per lane
// ---------------------------------------------------------------------------
__device__ __forceinline__ void gll16(const void* gsrc, void* ldst) {
    const __attribute__((address_space(1))) unsigned int* g =
        (const __attribute__((address_space(1))) unsigned int*)gsrc;
    __attribute__((address_space(3))) unsigned int* l =
        (__attribute__((address_space(3))) unsigned int*)(uintptr_t)ldst;
    __builtin_amdgcn_global_load_lds(g, l, 16, 0, 0);
}

// ---------------------------------------------------------------------------
// prep_A: A[M][C][P] f32  ->  Abf[(m*64+p)][c] bf16   (transpose C<->P + cast)
// ---------------------------------------------------------------------------
__global__ void prep_A_kernel(const float* __restrict__ A, bf16* __restrict__ Abf) {
    __shared__ float lds[128 * 65];
    const int m = blockIdx.x;
    const int t = threadIdx.x;
    const float* __restrict__ Am = A + (size_t)m * (Cdim * Pdim);

#pragma unroll
    for (int i = 0; i < 8; ++i) {
        int v = t + i * 256;
        int gidx = v * 4;
        int c = gidx >> 6, p = gidx & 63;
        float4 val = *reinterpret_cast<const float4*>(Am + gidx);
        float* dst = &lds[c * 65 + p];
        dst[0] = val.x; dst[1] = val.y; dst[2] = val.z; dst[3] = val.w;
    }
    __syncthreads();

    bf16* __restrict__ dstm = Abf + (size_t)m * (Pdim * Cdim);
#pragma unroll
    for (int i = 0; i < 16; ++i) {
        int pr = t + i * 256;
        int p = pr >> 6;
        int c = (pr & 63) << 1;
        float f0 = lds[c * 65 + p];
        float f1 = lds[(c + 1) * 65 + p];
        union { bf16 h[2]; unsigned u; } pk;
        pk.h[0] = __float2bfloat16(f0);
        pk.h[1] = __float2bfloat16(f1);
        *reinterpret_cast<unsigned*>(dstm + p * Cdim + c) = pk.u;
    }
}

// ---------------------------------------------------------------------------
// prep_G: Gbf[(n*64+q)][d] = bf16( sum_c B[n][c][q] * Wg[c][d] )
// ---------------------------------------------------------------------------
__global__ void prep_G_kernel(const float* __restrict__ B, const float* __restrict__ Wg,
                              bf16* __restrict__ Gbf) {
    __shared__ float ldsB[128 * 65];
    const int n  = blockIdx.x >> 2;
    const int q0 = (blockIdx.x & 3) * 16;
    const int t = threadIdx.x;
    const float* __restrict__ Bn = B + (size_t)n * (Cdim * Pdim);

#pragma unroll
    for (int i = 0; i < 8; ++i) {
        int v = t + i * 256;
        int gidx = v * 4;
        int c = gidx >> 6, q = gidx & 63;
        float4 val = *reinterpret_cast<const float4*>(Bn + gidx);
        float* dst = &ldsB[c * 65 + q];
        dst[0] = val.x; dst[1] = val.y; dst[2] = val.z; dst[3] = val.w;
    }
    __syncthreads();

    const int d  = t & 127;
    const int qb = q0 + (t >> 7) * 8;
    float acc[8] = {0.f, 0.f, 0.f, 0.f, 0.f, 0.f, 0.f, 0.f};
    for (int c = 0; c < 128; ++c) {
        float w = Wg[c * 128 + d];
#pragma unroll
        for (int qi = 0; qi < 8; ++qi)
            acc[qi] = fmaf(ldsB[c * 65 + qb + qi], w, acc[qi]);
    }
#pragma unroll
    for (int qi = 0; qi < 8; ++qi)
        Gbf[(size_t)(n * 64 + qb + qi) * Cdim + d] = __float2bfloat16(acc[qi]);
}

// ---------------------------------------------------------------------------
// gemm_max v4: barrier-free steady state.
// Block = one m (64 A-rows). A staged ONCE to swizzled LDS (16 KB), then each
// wave free-runs 16 steps; step = one n: G-frags (16 x bf16x8) streamed from
// L2 into register double-buffer P/Q (static names), 64 MFMA, max-epilogue.
// Swapped operands mfma(G, A, acc): D-row = q, D-col = p -> max over q =
// 15 in-lane fmax + shfl_xor(16) + shfl_xor(32).  ks==0 uses literal-0 C.
// No barriers / no inline-asm waitcnt after the single __syncthreads().
// ---------------------------------------------------------------------------
__global__ __launch_bounds__(256, 2)
void gemm_max_kernel(const bf16* __restrict__ Abf, const bf16* __restrict__ Gbf,
                     float* __restrict__ out) {
    __shared__ bf16 sA[64 * 128];   // 16 KB, 256 B/row, 16B-chunk XOR swizzle
    const int tid  = threadIdx.x;
    const int lane = tid & 63;
    const int w    = tid >> 6;            // wave 0..3 -> n = step*4 + w
    const int rr = lane & 15, g = lane >> 4;
    const int blk = blockIdx.x;           // = m

    // ---- stage A once: LDS[row][b] = A[row][b ^ ((row&7)<<4)] ----
    const char* Ab = (const char*)(Abf + (size_t)blk * 64 * 128);
#pragma unroll
    for (int j = 0; j < 4; ++j) {
        int f = (j * 256 + tid) * 16;          // 0..16383
        int row = f >> 8;                      // 256 B rows
        int inner = (f & 255) ^ ((row & 7) << 4);
        gll16(Ab + row * 256 + inner, (char*)sA + f);
    }

    f32x4 acc[4][4];                            // [qt][pt]
    bf16x8 P[4][4], Q[4][4];                    // G-frags [qt][ks], dbuf

    auto loadG = [&](bf16x8 (&dst)[4][4], int n) {
        const bf16* base = Gbf + ((size_t)n * 64 + rr) * 128 + g * 8;
#pragma unroll
        for (int qt = 0; qt < 4; ++qt)
#pragma unroll
            for (int ks = 0; ks < 4; ++ks)
                dst[qt][ks] = *reinterpret_cast<const bf16x8*>(base + qt * 16 * 128 + ks * 32);
    };

    const char* sAc = (const char*)sA;
    auto compute = [&](const bf16x8 (&gf)[4][4]) {
#pragma unroll
        for (int ks = 0; ks < 4; ++ks) {
            bf16x8 a[4];
#pragma unroll
            for (int pt = 0; pt < 4; ++pt)
                a[pt] = *reinterpret_cast<const bf16x8*>(
                    sAc + (pt * 16 + rr) * 256 + ((ks * 64 + g * 16) ^ ((rr & 7) << 4)));
#pragma unroll
            for (int qt = 0; qt < 4; ++qt)
#pragma unroll
                for (int pt = 0; pt < 4; ++pt)
                    acc[qt][pt] = __builtin_amdgcn_mfma_f32_16x16x32_bf16(
                        gf[qt][ks], a[pt],
                        ks == 0 ? (f32x4){0.f, 0.f, 0.f, 0.f} : acc[qt][pt], 0, 0, 0);
        }
    };

    auto epilogue = [&](int n) {
        float* ob = out + (size_t)blk * 4096 + n * 64;
#pragma unroll
        for (int pt = 0; pt < 4; ++pt) {
            float v = acc[0][pt][0];
#pragma unroll
            for (int qt = 0; qt < 4; ++qt)
#pragma unroll
                for (int j = 0; j < 4; ++j)
                    if (qt || j) v = fmaxf(v, acc[qt][pt][j]);
            v = fmaxf(v, __shfl_xor(v, 16));   // fold lane-groups g: 0<->1, 2<->3
            v = fmaxf(v, __shfl_xor(v, 32));   // fold g: {0,1}<->{2,3}
            if (g == 0) ob[pt * 16 + rr] = fmaxf(v, 0.f) + EPS_ADD;
        }
    };

    loadG(P, w);          // n for step 0
    __syncthreads();      // drains A-stage (and P) once; last barrier in kernel

    for (int sp = 0; sp < 8; ++sp) {
        const int n0 = sp * 8 + w;                    // step 2sp
        const int n1 = sp * 8 + 4 + w;                // step 2sp+1
        const int n2 = (((2 * sp + 2) & 15) << 2) + w; // step 2sp+2 (wraps)
        loadG(Q, n1);
        compute(P);
        epilogue(n0);
        loadG(P, n2);     // harmless wrap-reload on the last pair
        compute(Q);
        epilogue(n1);
    }
}

// ---------------------------------------------------------------------------
extern "C" void kernel_launch(void* const* d_in, const int* in_sizes, int n_in,
                              void* d_out, int out_size, void* d_ws, size_t ws_size,
                              hipStream_t stream) {
    const float* A  = (const float*)d_in[0];
    const float* B  = (const float*)d_in[1];
    const float* Wg = (const float*)d_in[2];
    float* out = (float*)d_out;

    bf16* Abf = (bf16*)d_ws;                                        // 32768 x 128 bf16 = 8 MiB
    bf16* Gbf = (bf16*)((char*)d_ws + (size_t)Mdim * Pdim * Cdim * sizeof(bf16)); // 4096 x 128 bf16

    prep_A_kernel<<<Mdim, 256, 0, stream>>>(A, Abf);
    prep_G_kernel<<<256, 256, 0, stream>>>(B, Wg, Gbf);
    gemm_max_kernel<<<Mdim, 256, 0, stream>>>(Abf, Gbf, out);   // 512 blocks = one m each
}

// Round 8
// 56.308 us; speedup vs baseline: 1.4964x; 1.4964x over previous
//
#include <hip/hip_runtime.h>
#include <hip/hip_bf16.h>
#include <stdint.h>

typedef __attribute__((ext_vector_type(8))) short bf16x8;
typedef __attribute__((ext_vector_type(4))) float f32x4;
using bf16 = __hip_bfloat16;

static constexpr int Mdim = 512;   // A batch
static constexpr int Ndim = 64;    // B batch
static constexpr int Cdim = 128;   // channels (K of the GEMM)
static constexpr int Pdim = 64;    // H*W positions
static constexpr float EPS_ADD = 0.001f;

#define SB0 __builtin_amdgcn_sched_barrier(0)
#define WAITV(N) asm volatile("s_waitcnt vmcnt(" #N ")" ::: "memory")

// ---------------------------------------------------------------------------
// async global->LDS, 16B per lane
// ---------------------------------------------------------------------------
__device__ __forceinline__ void gll16(const void* gsrc, void* ldst) {
    const __attribute__((address_space(1))) unsigned int* g =
        (const __attribute__((address_space(1))) unsigned int*)gsrc;
    __attribute__((address_space(3))) unsigned int* l =
        (__attribute__((address_space(3))) unsigned int*)(uintptr_t)ldst;
    __builtin_amdgcn_global_load_lds(g, l, 16, 0, 0);
}

// ---------------------------------------------------------------------------
// prep_A: A[M][C][P] f32  ->  Abf[(m*64+p)][c] bf16   (transpose C<->P + cast)
// ---------------------------------------------------------------------------
__global__ void prep_A_kernel(const float* __restrict__ A, bf16* __restrict__ Abf) {
    __shared__ float lds[128 * 65];
    const int m = blockIdx.x;
    const int t = threadIdx.x;
    const float* __restrict__ Am = A + (size_t)m * (Cdim * Pdim);

#pragma unroll
    for (int i = 0; i < 8; ++i) {
        int v = t + i * 256;
        int gidx = v * 4;
        int c = gidx >> 6, p = gidx & 63;
        float4 val = *reinterpret_cast<const float4*>(Am + gidx);
        float* dst = &lds[c * 65 + p];
        dst[0] = val.x; dst[1] = val.y; dst[2] = val.z; dst[3] = val.w;
    }
    __syncthreads();

    bf16* __restrict__ dstm = Abf + (size_t)m * (Pdim * Cdim);
#pragma unroll
    for (int i = 0; i < 16; ++i) {
        int pr = t + i * 256;
        int p = pr >> 6;
        int c = (pr & 63) << 1;
        float f0 = lds[c * 65 + p];
        float f1 = lds[(c + 1) * 65 + p];
        union { bf16 h[2]; unsigned u; } pk;
        pk.h[0] = __float2bfloat16(f0);
        pk.h[1] = __float2bfloat16(f1);
        *reinterpret_cast<unsigned*>(dstm + p * Cdim + c) = pk.u;
    }
}

// ---------------------------------------------------------------------------
// prep_G: Gbf[(n*64+q)][d] = bf16( sum_c B[n][c][q] * Wg[c][d] )
// ---------------------------------------------------------------------------
__global__ void prep_G_kernel(const float* __restrict__ B, const float* __restrict__ Wg,
                              bf16* __restrict__ Gbf) {
    __shared__ float ldsB[128 * 65];
    const int n  = blockIdx.x >> 2;
    const int q0 = (blockIdx.x & 3) * 16;
    const int t = threadIdx.x;
    const float* __restrict__ Bn = B + (size_t)n * (Cdim * Pdim);

#pragma unroll
    for (int i = 0; i < 8; ++i) {
        int v = t + i * 256;
        int gidx = v * 4;
        int c = gidx >> 6, q = gidx & 63;
        float4 val = *reinterpret_cast<const float4*>(Bn + gidx);
        float* dst = &ldsB[c * 65 + q];
        dst[0] = val.x; dst[1] = val.y; dst[2] = val.z; dst[3] = val.w;
    }
    __syncthreads();

    const int d  = t & 127;
    const int qb = q0 + (t >> 7) * 8;
    float acc[8] = {0.f, 0.f, 0.f, 0.f, 0.f, 0.f, 0.f, 0.f};
    for (int c = 0; c < 128; ++c) {
        float w = Wg[c * 128 + d];
#pragma unroll
        for (int qi = 0; qi < 8; ++qi)
            acc[qi] = fmaf(ldsB[c * 65 + qb + qi], w, acc[qi]);
    }
#pragma unroll
    for (int qi = 0; qi < 8; ++qi)
        Gbf[(size_t)(n * 64 + qb + qi) * Cdim + d] = __float2bfloat16(acc[qi]);
}

// ---------------------------------------------------------------------------
// gemm_max v6: big-tile, VMEM-traffic-minimal.
// Block = 512 thr (8 waves) owns BM=32 m's (2048 rows) x BN=4 n's (256 cols).
//  - G (4 n's, 64KB) staged ONCE -> LDS (linear); each wave's 16 G-frags
//    then loaded ONCE into registers (reused all 32 m-steps).
//  - A streamed: 16KB per m-step through 3 rolling swizzled LDS bufs,
//    dist-2 prefetch, uniform vmcnt(4), ONE barrier per step.
//  - wave (nw,h) = n-index nw, p-half h: mfma(G,A) -> D row=q, col=p;
//    acc[qt][pt] 4x2 f32x4; max over q = 16 in-lane fmax + shfl 16,32.
// Traffic: 256 blocks x (512KB A + 64KB G) = 144MB (~4x less than v4).
// Per-CU: 8192 MFMA = 39.7k cyc vs 512KB stage; compute-bound by design.
// LDS 64 + 3*16 = 112KB -> 1 block/CU; grid 256 = 1/CU exactly.
// bid = bn*16+bm -> xcd = bid%8 = bm%8: all bn-blocks of one bm (shared
// A-group) land on one XCD's L2.
// vmcnt ledger (per wave, per step: stores(2) then stage(2)):
//   W(0)=2 (drain A-s0, leave A-s1), W(1..30)=4 (drain stage(s), leave
//   s-1's stores+stage(s+1)), W(31)=2 (s30 issued no stage).
// ---------------------------------------------------------------------------
__global__ __launch_bounds__(512, 2)
void gemm_max_kernel(const bf16* __restrict__ Abf, const bf16* __restrict__ Gbf,
                     float* __restrict__ out) {
    __shared__ bf16 sG[4 * 64 * 128];     // 64KB, linear [n][q][c]
    __shared__ bf16 sA[3][64 * 128];      // 3 x 16KB rolling, 16B-chunk XOR swizzle
    const int tid  = threadIdx.x;
    const int lane = tid & 63;
    const int w    = tid >> 6;            // 0..7
    const int nw = w >> 1, h = w & 1;     // wave: n-index (0..3), p-half (0..1)
    const int rr = lane & 15, g = lane >> 4;
    const int bm = blockIdx.x & 15;       // 16 m-groups of 32 m's
    const int bn = blockIdx.x >> 4;       // 16 n-groups of 4 n's

    // ---- prologue staging: G first (oldest), then A steps 0,1 ----
    const char* Gsrc = (const char*)Gbf + (size_t)bn * 65536;
#pragma unroll
    for (int i = 0; i < 8; ++i) {
        int f = (i * 512 + tid) * 16;
        gll16(Gsrc + f, (char*)sG + f);
    }
    const char* Abase = (const char*)Abf + (size_t)bm * 32 * 16384;
    auto stageA = [&](int s) {
        char* dst = (char*)&sA[s % 3][0];
        const char* src = Abase + (size_t)s * 16384;
#pragma unroll
        for (int i = 0; i < 2; ++i) {
            int f = (i * 512 + tid) * 16;
            int row = f >> 8;                          // 64 rows x 256B
            int inner = (f & 255) ^ ((row & 7) << 4);  // pre-swizzled source
            gll16(src + row * 256 + inner, dst + f);
        }
    };
    stageA(0);
    stageA(1);

    // wait G staged (leave the 4 A-loads in flight), then G-frags -> regs
    WAITV(4); __builtin_amdgcn_s_barrier(); SB0;
    bf16x8 gf[4][4];   // [qt][ks], resident all 32 steps
    {
        const char* gb = (const char*)sG + nw * 16384 + rr * 256 + g * 16;
#pragma unroll
        for (int qt = 0; qt < 4; ++qt)
#pragma unroll
            for (int ks = 0; ks < 4; ++ks)
                gf[qt][ks] = *reinterpret_cast<const bf16x8*>(gb + qt * 4096 + ks * 64);
    }

    f32x4 acc[4][2];   // [qt][pt]

    auto compute = [&](int s) {
        const char* ab = (const char*)&sA[s % 3][0] + (h * 32 + rr) * 256;
#pragma unroll
        for (int ks = 0; ks < 4; ++ks) {
            const int off = (ks * 64 + g * 16) ^ ((rr & 7) << 4);   // row&7 == rr&7
            bf16x8 a0 = *reinterpret_cast<const bf16x8*>(ab + off);
            bf16x8 a1 = *reinterpret_cast<const bf16x8*>(ab + 16 * 256 + off);
#pragma unroll
            for (int qt = 0; qt < 4; ++qt) {
                acc[qt][0] = __builtin_amdgcn_mfma_f32_16x16x32_bf16(
                    gf[qt][ks], a0, ks == 0 ? (f32x4){0.f,0.f,0.f,0.f} : acc[qt][0], 0, 0, 0);
                acc[qt][1] = __builtin_amdgcn_mfma_f32_16x16x32_bf16(
                    gf[qt][ks], a1, ks == 0 ? (f32x4){0.f,0.f,0.f,0.f} : acc[qt][1], 0, 0, 0);
            }
        }
    };

    auto epilogue = [&](int s) {
        float* ob = out + (size_t)(bm * 32 + s) * 4096 + (bn * 4 + nw) * 64 + h * 32;
#pragma unroll
        for (int pt = 0; pt < 2; ++pt) {
            float v = acc[0][pt][0];
#pragma unroll
            for (int qt = 0; qt < 4; ++qt)
#pragma unroll
                for (int j = 0; j < 4; ++j)
                    if (qt || j) v = fmaxf(v, acc[qt][pt][j]);
            v = fmaxf(v, __shfl_xor(v, 16));
            v = fmaxf(v, __shfl_xor(v, 32));
            if (g == 0) ob[pt * 16 + rr] = fmaxf(v, 0.f) + EPS_ADD;
        }
    };

    // ---- step 0: need A-s0 (leave A-s1) ----
    WAITV(2); __builtin_amdgcn_s_barrier(); SB0;
    compute(0); epilogue(0); SB0; stageA(2); SB0;

    // ---- steady steps 1..29: uniform vmcnt(4) ----
    for (int s = 1; s <= 29; ++s) {
        WAITV(4); __builtin_amdgcn_s_barrier(); SB0;
        compute(s); epilogue(s); SB0; stageA(s + 2); SB0;
    }

    // ---- step 30 (no stage issued) ----
    WAITV(4); __builtin_amdgcn_s_barrier(); SB0;
    compute(30); epilogue(30); SB0;

    // ---- step 31: stage(31) sits among newest 4 -> vmcnt(2) ----
    WAITV(2); __builtin_amdgcn_s_barrier(); SB0;
    compute(31); epilogue(31);
}

// ---------------------------------------------------------------------------
extern "C" void kernel_launch(void* const* d_in, const int* in_sizes, int n_in,
                              void* d_out, int out_size, void* d_ws, size_t ws_size,
                              hipStream_t stream) {
    const float* A  = (const float*)d_in[0];
    const float* B  = (const float*)d_in[1];
    const float* Wg = (const float*)d_in[2];
    float* out = (float*)d_out;

    bf16* Abf = (bf16*)d_ws;                                        // 32768 x 128 bf16 = 8 MiB
    bf16* Gbf = (bf16*)((char*)d_ws + (size_t)Mdim * Pdim * Cdim * sizeof(bf16)); // 4096 x 128 bf16

    prep_A_kernel<<<Mdim, 256, 0, stream>>>(A, Abf);
    prep_G_kernel<<<256, 256, 0, stream>>>(B, Wg, Gbf);
    gemm_max_kernel<<<256, 512, 0, stream>>>(Abf, Gbf, out);   // 16 m-groups x 16 n-groups
}

// Round 9
// 53.686 us; speedup vs baseline: 1.5695x; 1.0488x over previous
//
#include <hip/hip_runtime.h>
#include <hip/hip_bf16.h>
#include <stdint.h>

typedef __attribute__((ext_vector_type(8))) short bf16x8;
typedef __attribute__((ext_vector_type(4))) float f32x4;
using bf16 = __hip_bfloat16;

static constexpr int Mdim = 512;   // A batch
static constexpr int Ndim = 64;    // B batch
static constexpr int Cdim = 128;   // channels (K of the GEMM)
static constexpr int Pdim = 64;    // H*W positions
static constexpr float EPS_ADD = 0.001f;

#define SB0 __builtin_amdgcn_sched_barrier(0)
#define WAITV(N) asm volatile("s_waitcnt vmcnt(" #N ")" ::: "memory")

// ---------------------------------------------------------------------------
// async global->LDS, 16B per lane
// ---------------------------------------------------------------------------
__device__ __forceinline__ void gll16(const void* gsrc, void* ldst) {
    const __attribute__((address_space(1))) unsigned int* g =
        (const __attribute__((address_space(1))) unsigned int*)gsrc;
    __attribute__((address_space(3))) unsigned int* l =
        (__attribute__((address_space(3))) unsigned int*)(uintptr_t)ldst;
    __builtin_amdgcn_global_load_lds(g, l, 16, 0, 0);
}

// ---------------------------------------------------------------------------
// prep (fused): blocks 0..511 do prep_A (one m each); 512..767 do prep_G.
// Shared 33KB LDS tile (same shape for both paths).
// prep_A: A[M][C][P] f32 -> Abf[(m*64+p)][c] bf16 (transpose C<->P + cast)
// prep_G: Gbf[(n*64+q)][d] = bf16( sum_c B[n][c][q] * Wg[c][d] )
// ---------------------------------------------------------------------------
__global__ void prep_kernel(const float* __restrict__ A, const float* __restrict__ B,
                            const float* __restrict__ Wg,
                            bf16* __restrict__ Abf, bf16* __restrict__ Gbf) {
    __shared__ float lds[128 * 65];
    const int t = threadIdx.x;

    if (blockIdx.x < 512) {
        const int m = blockIdx.x;
        const float* __restrict__ Am = A + (size_t)m * (Cdim * Pdim);
#pragma unroll
        for (int i = 0; i < 8; ++i) {
            int v = t + i * 256;
            int gidx = v * 4;
            int c = gidx >> 6, p = gidx & 63;
            float4 val = *reinterpret_cast<const float4*>(Am + gidx);
            float* dst = &lds[c * 65 + p];
            dst[0] = val.x; dst[1] = val.y; dst[2] = val.z; dst[3] = val.w;
        }
        __syncthreads();

        bf16* __restrict__ dstm = Abf + (size_t)m * (Pdim * Cdim);
#pragma unroll
        for (int i = 0; i < 16; ++i) {
            int pr = t + i * 256;
            int p = pr >> 6;
            int c = (pr & 63) << 1;
            float f0 = lds[c * 65 + p];
            float f1 = lds[(c + 1) * 65 + p];
            union { bf16 h[2]; unsigned u; } pk;
            pk.h[0] = __float2bfloat16(f0);
            pk.h[1] = __float2bfloat16(f1);
            *reinterpret_cast<unsigned*>(dstm + p * Cdim + c) = pk.u;
        }
    } else {
        const int nb = blockIdx.x - 512;
        const int n  = nb >> 2;
        const int q0 = (nb & 3) * 16;
        const float* __restrict__ Bn = B + (size_t)n * (Cdim * Pdim);
#pragma unroll
        for (int i = 0; i < 8; ++i) {
            int v = t + i * 256;
            int gidx = v * 4;
            int c = gidx >> 6, q = gidx & 63;
            float4 val = *reinterpret_cast<const float4*>(Bn + gidx);
            float* dst = &lds[c * 65 + q];
            dst[0] = val.x; dst[1] = val.y; dst[2] = val.z; dst[3] = val.w;
        }
        __syncthreads();

        const int d  = t & 127;
        const int qb = q0 + (t >> 7) * 8;
        float acc[8] = {0.f, 0.f, 0.f, 0.f, 0.f, 0.f, 0.f, 0.f};
        for (int c = 0; c < 128; ++c) {
            float w = Wg[c * 128 + d];
#pragma unroll
            for (int qi = 0; qi < 8; ++qi)
                acc[qi] = fmaf(lds[c * 65 + qb + qi], w, acc[qi]);
        }
#pragma unroll
        for (int qi = 0; qi < 8; ++qi)
            Gbf[(size_t)(n * 64 + qb + qi) * Cdim + d] = __float2bfloat16(acc[qi]);
    }
}

// ---------------------------------------------------------------------------
// gemm_max v7: v6 dataflow, more blocks/CU.
// Block = 256 thr (4 waves) owns BM=32 m's x BN=2 n's. Wave (nw,h).
//  - G frags -> REGISTERS directly from L2-resident Gbf (no sG LDS),
//    once per block, reused all 32 m-steps.
//  - A streamed: 16KB per m-step, 3 rolling swizzled LDS bufs (48KB total),
//    dist-2 prefetch, stage issued BEFORE epilogue, ONE barrier per step.
//  - mfma(G,A): D row=q, col=p; acc[4][2]; max over q = in-lane + shfl 16,32.
// LDS 48KB -> 3 blocks/CU; __launch_bounds__(256,3) -> 170-reg cap (v6 used
// 112 -> no spill). Grid 512 (2/CU avg): independent barrier domains per CU.
// bid = bn*16+bm, bid%8 = bm%8 -> same-A blocks share an XCD L2.
// vmcnt ledger (stage=4 gll16, epi=2 stores, order per step: stage,epi):
//   prologue G(16) A0(4) A1(4): WAITV(8) drains G.
//   step0 W(4) [leave A1]; step1 W(6); steps 2..30 W(8); step31 W(4).
// ---------------------------------------------------------------------------
__global__ __launch_bounds__(256, 3)
void gemm_max_kernel(const bf16* __restrict__ Abf, const bf16* __restrict__ Gbf,
                     float* __restrict__ out) {
    __shared__ bf16 sA[3][64 * 128];      // 3 x 16KB rolling, 16B-chunk XOR swizzle
    const int tid  = threadIdx.x;
    const int lane = tid & 63;
    const int w    = tid >> 6;            // 0..3
    const int nw = w >> 1, h = w & 1;     // n-index (0..1), p-half (0..1)
    const int rr = lane & 15, g = lane >> 4;
    const int bm = blockIdx.x & 15;       // 16 m-groups of 32 m's
    const int bn = blockIdx.x >> 4;       // 32 n-groups of 2 n's

    // ---- prologue: G-loads (oldest), then A steps 0,1 ----
    const bf16* Gp = Gbf + ((size_t)((bn * 2 + nw) * 64 + rr)) * 128 + g * 8;
    bf16x8 gf[4][4];   // [qt][ks]
#pragma unroll
    for (int qt = 0; qt < 4; ++qt)
#pragma unroll
        for (int ks = 0; ks < 4; ++ks)
            gf[qt][ks] = *reinterpret_cast<const bf16x8*>(Gp + qt * 16 * 128 + ks * 32);
    asm volatile("" ::: "memory");   // pin G-loads before stage issues

    const char* Abase = (const char*)Abf + (size_t)bm * 32 * 16384;
    auto stageA = [&](int s) {
        char* dst = (char*)&sA[s % 3][0];
        const char* src = Abase + (size_t)s * 16384;
#pragma unroll
        for (int i = 0; i < 4; ++i) {
            int f = (i * 256 + tid) * 16;
            int row = f >> 8;                          // 64 rows x 256B
            int inner = (f & 255) ^ ((row & 7) << 4);  // pre-swizzled source
            gll16(src + row * 256 + inner, dst + f);
        }
    };
    stageA(0);
    stageA(1);
    WAITV(8);   // G-regs complete (compiler also guards their uses)

    f32x4 acc[4][2];   // [qt][pt]

    auto compute = [&](int s) {
        const char* ab = (const char*)&sA[s % 3][0] + (h * 32 + rr) * 256;
#pragma unroll
        for (int ks = 0; ks < 4; ++ks) {
            const int off = (ks * 64 + g * 16) ^ ((rr & 7) << 4);   // row&7 == rr&7
            bf16x8 a0 = *reinterpret_cast<const bf16x8*>(ab + off);
            bf16x8 a1 = *reinterpret_cast<const bf16x8*>(ab + 16 * 256 + off);
#pragma unroll
            for (int qt = 0; qt < 4; ++qt) {
                acc[qt][0] = __builtin_amdgcn_mfma_f32_16x16x32_bf16(
                    gf[qt][ks], a0, ks == 0 ? (f32x4){0.f,0.f,0.f,0.f} : acc[qt][0], 0, 0, 0);
                acc[qt][1] = __builtin_amdgcn_mfma_f32_16x16x32_bf16(
                    gf[qt][ks], a1, ks == 0 ? (f32x4){0.f,0.f,0.f,0.f} : acc[qt][1], 0, 0, 0);
            }
        }
    };

    auto epilogue = [&](int s) {
        float* ob = out + (size_t)(bm * 32 + s) * 4096 + (bn * 2 + nw) * 64 + h * 32;
#pragma unroll
        for (int pt = 0; pt < 2; ++pt) {
            float v = acc[0][pt][0];
#pragma unroll
            for (int qt = 0; qt < 4; ++qt)
#pragma unroll
                for (int j = 0; j < 4; ++j)
                    if (qt || j) v = fmaxf(v, acc[qt][pt][j]);
            v = fmaxf(v, __shfl_xor(v, 16));
            v = fmaxf(v, __shfl_xor(v, 32));
            if (g == 0) ob[pt * 16 + rr] = fmaxf(v, 0.f) + EPS_ADD;
        }
    };

    // ---- step 0: need A-s0 (leave A-s1) ----
    WAITV(4); __builtin_amdgcn_s_barrier(); SB0;
    compute(0); SB0; stageA(2); epilogue(0); SB0;

    // ---- step 1 ----
    WAITV(6); __builtin_amdgcn_s_barrier(); SB0;
    compute(1); SB0; stageA(3); epilogue(1); SB0;

    // ---- steady steps 2..29 ----
    for (int s = 2; s <= 29; ++s) {
        WAITV(8); __builtin_amdgcn_s_barrier(); SB0;
        compute(s); SB0; stageA(s + 2); epilogue(s); SB0;
    }

    // ---- step 30 (no stage issued) ----
    WAITV(8); __builtin_amdgcn_s_barrier(); SB0;
    compute(30); epilogue(30); SB0;

    // ---- step 31 ----
    WAITV(4); __builtin_amdgcn_s_barrier(); SB0;
    compute(31); epilogue(31);
}

// ---------------------------------------------------------------------------
extern "C" void kernel_launch(void* const* d_in, const int* in_sizes, int n_in,
                              void* d_out, int out_size, void* d_ws, size_t ws_size,
                              hipStream_t stream) {
    const float* A  = (const float*)d_in[0];
    const float* B  = (const float*)d_in[1];
    const float* Wg = (const float*)d_in[2];
    float* out = (float*)d_out;

    bf16* Abf = (bf16*)d_ws;                                        // 32768 x 128 bf16 = 8 MiB
    bf16* Gbf = (bf16*)((char*)d_ws + (size_t)Mdim * Pdim * Cdim * sizeof(bf16)); // 4096 x 128 bf16

    prep_kernel<<<768, 256, 0, stream>>>(A, B, Wg, Abf, Gbf);
    gemm_max_kernel<<<512, 256, 0, stream>>>(Abf, Gbf, out);   // 16 bm x 32 bn
}

// Round 10
// 52.796 us; speedup vs baseline: 1.5960x; 1.0169x over previous
//
#include <hip/hip_runtime.h>
#include <hip/hip_bf16.h>
#include <stdint.h>

typedef __attribute__((ext_vector_type(8))) short bf16x8;
typedef __attribute__((ext_vector_type(4))) float f32x4;
typedef __attribute__((ext_vector_type(16))) float f32x16;
using bf16 = __hip_bfloat16;

static constexpr int Mdim = 512;   // A batch
static constexpr int Ndim = 64;    // B batch
static constexpr int Cdim = 128;   // channels (K of the GEMM)
static constexpr int Pdim = 64;    // H*W positions
static constexpr float EPS_ADD = 0.001f;

#define SB0 __builtin_amdgcn_sched_barrier(0)
#define WAITV(N) asm volatile("s_waitcnt vmcnt(" #N ")" ::: "memory")

// ---------------------------------------------------------------------------
// async global->LDS, 16B per lane
// ---------------------------------------------------------------------------
__device__ __forceinline__ void gll16(const void* gsrc, void* ldst) {
    const __attribute__((address_space(1))) unsigned int* g =
        (const __attribute__((address_space(1))) unsigned int*)gsrc;
    __attribute__((address_space(3))) unsigned int* l =
        (__attribute__((address_space(3))) unsigned int*)(uintptr_t)ldst;
    __builtin_amdgcn_global_load_lds(g, l, 16, 0, 0);
}

// ---------------------------------------------------------------------------
// prep (fused): blocks 0..511 do prep_A (one m each); 512..767 do prep_G.
// ---------------------------------------------------------------------------
__global__ void prep_kernel(const float* __restrict__ A, const float* __restrict__ B,
                            const float* __restrict__ Wg,
                            bf16* __restrict__ Abf, bf16* __restrict__ Gbf) {
    __shared__ float lds[128 * 65];
    const int t = threadIdx.x;

    if (blockIdx.x < 512) {
        const int m = blockIdx.x;
        const float* __restrict__ Am = A + (size_t)m * (Cdim * Pdim);
#pragma unroll
        for (int i = 0; i < 8; ++i) {
            int v = t + i * 256;
            int gidx = v * 4;
            int c = gidx >> 6, p = gidx & 63;
            float4 val = *reinterpret_cast<const float4*>(Am + gidx);
            float* dst = &lds[c * 65 + p];
            dst[0] = val.x; dst[1] = val.y; dst[2] = val.z; dst[3] = val.w;
        }
        __syncthreads();

        bf16* __restrict__ dstm = Abf + (size_t)m * (Pdim * Cdim);
#pragma unroll
        for (int i = 0; i < 16; ++i) {
            int pr = t + i * 256;
            int p = pr >> 6;
            int c = (pr & 63) << 1;
            float f0 = lds[c * 65 + p];
            float f1 = lds[(c + 1) * 65 + p];
            union { bf16 h[2]; unsigned u; } pk;
            pk.h[0] = __float2bfloat16(f0);
            pk.h[1] = __float2bfloat16(f1);
            *reinterpret_cast<unsigned*>(dstm + p * Cdim + c) = pk.u;
        }
    } else {
        const int nb = blockIdx.x - 512;
        const int n  = nb >> 2;
        const int q0 = (nb & 3) * 16;
        const float* __restrict__ Bn = B + (size_t)n * (Cdim * Pdim);
#pragma unroll
        for (int i = 0; i < 8; ++i) {
            int v = t + i * 256;
            int gidx = v * 4;
            int c = gidx >> 6, q = gidx & 63;
            float4 val = *reinterpret_cast<const float4*>(Bn + gidx);
            float* dst = &lds[c * 65 + q];
            dst[0] = val.x; dst[1] = val.y; dst[2] = val.z; dst[3] = val.w;
        }
        __syncthreads();

        const int d  = t & 127;
        const int qb = q0 + (t >> 7) * 8;
        float acc[8] = {0.f, 0.f, 0.f, 0.f, 0.f, 0.f, 0.f, 0.f};
        for (int c = 0; c < 128; ++c) {
            float w = Wg[c * 128 + d];
#pragma unroll
            for (int qi = 0; qi < 8; ++qi)
                acc[qi] = fmaf(lds[c * 65 + qb + qi], w, acc[qi]);
        }
#pragma unroll
        for (int qi = 0; qi < 8; ++qi)
            Gbf[(size_t)(n * 64 + qb + qi) * Cdim + d] = __float2bfloat16(acc[qi]);
    }
}

// ---------------------------------------------------------------------------
// gemm_max v8: 32x32x16 MFMA, BM=16, BN=2, grid 1024 (4 blocks/CU).
//  - Wave (nw,h): n = bn*2+nw, p-rows h*32..h*32+31; per step (one m):
//    8 ds_read_b128 (shared by 2 q-tiles), 16 MFMA 32x32x16, tiny epilogue.
//  - gf[2][8] in registers (loaded once from L2-resident Gbf).
//  - A: 2-buf x 16KB swizzled LDS, dist-1 prefetch, ONE WAITV + ONE barrier
//    per step. WAIT-before-barrier publishes all waves' stage writes;
//    compute-before-barrier retires reads before the next-buf overwrite.
//  - Epilogue: 31 in-lane fmax + shfl_xor(32) + coalesced 32-lane store.
//    32x32 C/D (m74/m101): col=lane&31 (=p), row=(reg&3)+8*(reg>>2)+4*hi (=q);
//    A/B operands: lane&31 -> row/col, lane>>5 -> k-octet.
// vmcnt ledger: prologue stage0(8)+gf(16) -> step0 WAITV(16) drains stage0
// (gf drained by compiler before first MFMA use). Steps 1..15: outstanding =
// stage(s) 8 + store(s-1) 1 -> WAITV(1).
// bid: mg = bid&31, bn = bid>>5 -> bid%8 = mg%8: same-A blocks share an XCD.
// ---------------------------------------------------------------------------
__global__ __launch_bounds__(256, 2)
void gemm_max_kernel(const bf16* __restrict__ Abf, const bf16* __restrict__ Gbf,
                     float* __restrict__ out) {
    __shared__ bf16 sA[2][64 * 128];      // 2 x 16KB, 16B-chunk XOR swizzle
    const int tid  = threadIdx.x;
    const int lane = tid & 63;
    const int w    = tid >> 6;            // 0..3
    const int nw = w >> 1, h = w & 1;
    const int l31 = lane & 31, hi = lane >> 5;
    const int mg = blockIdx.x & 31;       // 32 m-groups of 16 m's
    const int bn = blockIdx.x >> 5;       // 32 n-pairs
    const int n  = bn * 2 + nw;

    // ---- prologue: stage(0) first (oldest vmcnt), then gf (compiler-tracked)
    const char* Abase = (const char*)Abf + (size_t)mg * 16 * 16384;
    auto stageA = [&](int s) {
        char* dst = (char*)&sA[s & 1][0];
        const char* src = Abase + (size_t)s * 16384;
#pragma unroll
        for (int i = 0; i < 4; ++i) {
            int f = (i * 256 + tid) * 16;
            int row = f >> 8;                          // 64 rows x 256B
            int inner = (f & 255) ^ ((row & 7) << 4);  // pre-swizzled source
            gll16(src + row * 256 + inner, dst + f);
        }
    };
    stageA(0);

    bf16x8 gf[2][8];   // [q-tile][ks], resident all 16 steps
    {
        const bf16* Gp = Gbf + ((size_t)n * 64 + l31) * 128 + hi * 8;
#pragma unroll
        for (int qt = 0; qt < 2; ++qt)
#pragma unroll
            for (int ks = 0; ks < 8; ++ks)
                gf[qt][ks] = *reinterpret_cast<const bf16x8*>(Gp + qt * 32 * 128 + ks * 16);
    }

    f32x16 acc[2];
    const f32x16 z16 = {0.f,0.f,0.f,0.f,0.f,0.f,0.f,0.f,0.f,0.f,0.f,0.f,0.f,0.f,0.f,0.f};

    auto compute = [&](int s) {
        const char* ab = (const char*)&sA[s & 1][0] + (h * 32 + l31) * 256;
#pragma unroll
        for (int ks = 0; ks < 8; ++ks) {
            const int off = (ks * 32 + hi * 16) ^ ((l31 & 7) << 4);
            bf16x8 a = *reinterpret_cast<const bf16x8*>(ab + off);
            acc[0] = __builtin_amdgcn_mfma_f32_32x32x16_bf16(
                gf[0][ks], a, ks == 0 ? z16 : acc[0], 0, 0, 0);
            acc[1] = __builtin_amdgcn_mfma_f32_32x32x16_bf16(
                gf[1][ks], a, ks == 0 ? z16 : acc[1], 0, 0, 0);
        }
    };

    auto epilogue = [&](int s) {
        float v = acc[0][0];
#pragma unroll
        for (int j = 1; j < 16; ++j) v = fmaxf(v, acc[0][j]);
#pragma unroll
        for (int j = 0; j < 16; ++j) v = fmaxf(v, acc[1][j]);
        v = fmaxf(v, __shfl_xor(v, 32));   // combine q-row halves (hi 0<->1)
        if (hi == 0)
            out[(size_t)(mg * 16 + s) * 4096 + n * 64 + h * 32 + l31] =
                fmaxf(v, 0.f) + EPS_ADD;
    };

    // ---- step 0: drain stage(0), leave gf to compiler waits ----
    WAITV(16); __builtin_amdgcn_s_barrier(); SB0;
    compute(0); SB0; stageA(1); epilogue(0); SB0;

    // ---- steps 1..14: uniform WAITV(1) (keep store(s-1)) ----
    for (int s = 1; s <= 14; ++s) {
        WAITV(1); __builtin_amdgcn_s_barrier(); SB0;
        compute(s); SB0; stageA(s + 1); epilogue(s); SB0;
    }

    // ---- step 15 ----
    WAITV(1); __builtin_amdgcn_s_barrier(); SB0;
    compute(15); epilogue(15);
}

// ---------------------------------------------------------------------------
extern "C" void kernel_launch(void* const* d_in, const int* in_sizes, int n_in,
                              void* d_out, int out_size, void* d_ws, size_t ws_size,
                              hipStream_t stream) {
    const float* A  = (const float*)d_in[0];
    const float* B  = (const float*)d_in[1];
    const float* Wg = (const float*)d_in[2];
    float* out = (float*)d_out;

    bf16* Abf = (bf16*)d_ws;                                        // 32768 x 128 bf16 = 8 MiB
    bf16* Gbf = (bf16*)((char*)d_ws + (size_t)Mdim * Pdim * Cdim * sizeof(bf16)); // 4096 x 128 bf16

    prep_kernel<<<768, 256, 0, stream>>>(A, B, Wg, Abf, Gbf);
    gemm_max_kernel<<<1024, 256, 0, stream>>>(Abf, Gbf, out);   // 32 mg x 32 bn
}